// Round 3
// baseline (495.676 us; speedup 1.0000x reference)
//
#include <hip/hip_runtime.h>
#include <hip/hip_bf16.h>

#define BATCH  16384
#define NSITES 4096
#define HALFN  2048
#define HDIM   128
#define SLOPE  0.2f
#define BM     32

typedef __attribute__((ext_vector_type(8))) short bf16x8;
typedef __attribute__((ext_vector_type(4))) float f32x4;

// ws layout (bf16 element offsets), all matrices stored TRANSPOSED as [N][K]
#define OFF_SW0T 0         // [128][2048]
#define OFF_TW0T 262144
#define OFF_SW1T 524288    // [128][128]
#define OFF_TW1T 540672
#define OFF_SW2T 557056    // [2048][128]
#define OFF_TW2T 819200

__device__ __forceinline__ unsigned short f2bf(float f) {
    unsigned int u = __float_as_uint(f);
    u += 0x7FFFu + ((u >> 16) & 1u);   // round-to-nearest-even
    return (unsigned short)(u >> 16);
}

__global__ void conv_w(const float* __restrict__ sW0, const float* __restrict__ sW1,
                       const float* __restrict__ sW2, const float* __restrict__ tW0,
                       const float* __restrict__ tW1, const float* __restrict__ tW2,
                       unsigned short* __restrict__ ws) {
    const int total = 262144 + 16384 + 262144;
    for (int i = blockIdx.x * blockDim.x + threadIdx.x; i < total;
         i += gridDim.x * blockDim.x) {
        if (i < 262144) {                    // W0 [2048][128] -> [128][2048]
            int k = i >> 7, n = i & 127;
            ws[OFF_SW0T + n * 2048 + k] = f2bf(sW0[i]);
            ws[OFF_TW0T + n * 2048 + k] = f2bf(tW0[i]);
        } else if (i < 262144 + 16384) {     // W1 [128][128] -> [128][128]^T
            int j = i - 262144;
            int k = j >> 7, n = j & 127;
            ws[OFF_SW1T + n * 128 + k] = f2bf(sW1[j]);
            ws[OFF_TW1T + n * 128 + k] = f2bf(tW1[j]);
        } else {                             // W2 [128][2048] -> [2048][128]
            int j = i - (262144 + 16384);
            int k = j >> 11, n = j & 2047;
            ws[OFF_SW2T + n * 128 + k] = f2bf(sW2[j]);
            ws[OFF_TW2T + n * 128 + k] = f2bf(tW2[j]);
        }
    }
}

// Load one MFMA A-fragment (8 consecutive A-sites for this lane's row) directly
// from global z. rl = lattice row (= a_index/32); A-sites sit at even (rl even)
// or odd (rl odd) float slots of the aligned 64-B window — parity is uniform
// across the wave for a given fragment.
__device__ __forceinline__ bf16x8 load_afrag(const float4* __restrict__ zf4,
                                             size_t rowbase, int rl, int l4) {
    const float4* s = zf4 + rowbase + rl * 16 + l4 * 4;
    const float4 v0 = s[0], v1 = s[1], v2 = s[2], v3 = s[3];
    const int par = rl & 1;
    const float2 p0 = par ? make_float2(v0.y, v0.w) : make_float2(v0.x, v0.z);
    const float2 p1 = par ? make_float2(v1.y, v1.w) : make_float2(v1.x, v1.z);
    const float2 p2 = par ? make_float2(v2.y, v2.w) : make_float2(v2.x, v2.z);
    const float2 p3 = par ? make_float2(v3.y, v3.w) : make_float2(v3.x, v3.z);
    union { bf16x8 v; __hip_bfloat162 h[4]; } u;
    u.h[0] = __float22bfloat162_rn(p0);
    u.h[1] = __float22bfloat162_rn(p1);
    u.h[2] = __float22bfloat162_rn(p2);
    u.h[3] = __float22bfloat162_rn(p3);
    return u.v;
}

__global__ __launch_bounds__(256, 2) void coupling_main(
    const float* __restrict__ z,
    const float* __restrict__ s_b2,
    const float* __restrict__ t_b2,
    const unsigned short* __restrict__ ws,
    float* __restrict__ f_out,
    float* __restrict__ d_vec) {

    __shared__ __align__(16) unsigned short Hs[BM * 128];   // h (s-net), swizzled
    __shared__ __align__(16) unsigned short Ht[BM * 128];   // h (t-net), swizzled
    __shared__ float Dred[128];

    const int tid  = threadIdx.x;
    const int wave = tid >> 6;
    const int lane = tid & 63;
    const int l15  = lane & 15;
    const int l4   = lane >> 4;
    const int brow = blockIdx.x * BM;

    const float2* __restrict__ zf2 = (const float2*)z;
    const float4* __restrict__ zf4 = (const float4*)z;
    float2* __restrict__ ff2 = (float2*)f_out;

    const unsigned short* W0T[2] = { ws + OFF_SW0T, ws + OFF_TW0T };
    const unsigned short* W1T[2] = { ws + OFF_SW1T, ws + OFF_TW1T };
    const unsigned short* W2T[2] = { ws + OFF_SW2T, ws + OFF_TW2T };

    const size_t rb0 = (size_t)(brow + l15) * 1024;        // m2=0 row base (float4)
    const size_t rb1 = (size_t)(brow + 16 + l15) * 1024;   // m2=1 row base

    // ---------------- layer 0: h0 = leaky(z_a @ W0), direct-from-global A ----------------
    f32x4 acc0[2][2][2] = {};   // [net][m2][n2]
    bf16x8 afc[2][4];           // current chunk's A-frags [m2][k2]
    #pragma unroll
    for (int k2 = 0; k2 < 4; ++k2) {
        afc[0][k2] = load_afrag(zf4, rb0, k2, l4);
        afc[1][k2] = load_afrag(zf4, rb1, k2, l4);
    }

    #pragma unroll 1
    for (int it = 0; it < 16; ++it) {
        const int kk = it * 128;
        bf16x8 afn[2][4];
        if (it < 15) {
            #pragma unroll
            for (int k2 = 0; k2 < 4; ++k2) {
                afn[0][k2] = load_afrag(zf4, rb0, (it + 1) * 4 + k2, l4);
                afn[1][k2] = load_afrag(zf4, rb1, (it + 1) * 4 + k2, l4);
            }
        }
        #pragma unroll
        for (int net = 0; net < 2; ++net)
            #pragma unroll
            for (int n2 = 0; n2 < 2; ++n2) {
                const int n = wave * 32 + n2 * 16 + l15;
                #pragma unroll
                for (int k2 = 0; k2 < 4; ++k2) {
                    const bf16x8 w = *(const bf16x8*)&W0T[net][(size_t)n * 2048 + kk + k2 * 32 + l4 * 8];
                    #pragma unroll
                    for (int m2 = 0; m2 < 2; ++m2)
                        acc0[net][m2][n2] = __builtin_amdgcn_mfma_f32_16x16x32_bf16(
                            afc[m2][k2], w, acc0[net][m2][n2], 0, 0, 0);
                }
            }
        #pragma unroll
        for (int m2 = 0; m2 < 2; ++m2)
            #pragma unroll
            for (int k2 = 0; k2 < 4; ++k2)
                afc[m2][k2] = afn[m2][k2];
    }

    // leaky relu, h0 -> LDS (swizzled)
    #pragma unroll
    for (int net = 0; net < 2; ++net) {
        unsigned short* H = net ? Ht : Hs;
        #pragma unroll
        for (int m2 = 0; m2 < 2; ++m2)
            #pragma unroll
            for (int n2 = 0; n2 < 2; ++n2)
                #pragma unroll
                for (int r = 0; r < 4; ++r) {
                    float v = acc0[net][m2][n2][r];
                    v = v > 0.0f ? v : SLOPE * v;
                    const int row = m2 * 16 + l4 * 4 + r;
                    const int col = wave * 32 + n2 * 16 + l15;
                    H[row * 128 + (col ^ ((row & 7) << 3))] = f2bf(v);
                }
    }
    __syncthreads();

    // ---------------- layer 1: h1 = leaky(h0 @ W1) ----------------
    f32x4 acc1[2][2][2] = {};
    #pragma unroll
    for (int k4 = 0; k4 < 4; ++k4) {
        bf16x8 ah[2][2];   // [net][m2]
        #pragma unroll
        for (int m2 = 0; m2 < 2; ++m2) {
            const int row = m2 * 16 + l15;
            const int e = row * 128 + ((k4 * 32 + l4 * 8) ^ ((row & 7) << 3));
            ah[0][m2] = *(const bf16x8*)&Hs[e];
            ah[1][m2] = *(const bf16x8*)&Ht[e];
        }
        #pragma unroll
        for (int net = 0; net < 2; ++net)
            #pragma unroll
            for (int n2 = 0; n2 < 2; ++n2) {
                const int n = wave * 32 + n2 * 16 + l15;
                const bf16x8 w = *(const bf16x8*)&W1T[net][n * 128 + k4 * 32 + l4 * 8];
                #pragma unroll
                for (int m2 = 0; m2 < 2; ++m2)
                    acc1[net][m2][n2] = __builtin_amdgcn_mfma_f32_16x16x32_bf16(
                        ah[net][m2], w, acc1[net][m2][n2], 0, 0, 0);
            }
    }
    __syncthreads();   // all h0 reads done before overwrite
    #pragma unroll
    for (int net = 0; net < 2; ++net) {
        unsigned short* H = net ? Ht : Hs;
        #pragma unroll
        for (int m2 = 0; m2 < 2; ++m2)
            #pragma unroll
            for (int n2 = 0; n2 < 2; ++n2)
                #pragma unroll
                for (int r = 0; r < 4; ++r) {
                    float v = acc1[net][m2][n2][r];
                    v = v > 0.0f ? v : SLOPE * v;
                    const int row = m2 * 16 + l4 * 4 + r;
                    const int col = wave * 32 + n2 * 16 + l15;
                    H[row * 128 + (col ^ ((row & 7) << 3))] = f2bf(v);
                }
    }
    __syncthreads();

    // ---------------- layer 2 + epilogue, 16 N-chunks of 128 cols ----------------
    float dsum[2][4] = {};
    #pragma unroll 1
    for (int c = 0; c < 16; ++c) {
        const int jw = c * 128 + wave * 32;   // this wave's 32 cols = lattice row jw>>5
        const int rl = jw >> 5;               // lattice row index
        const int evenA = 1 - (rl & 1);       // A-sites at even z-cols when row even

        // hoisted epilogue loads (independent of MFMAs below)
        float2 zv[2][2][4];
        float sb[2], tb[2];
        #pragma unroll
        for (int n2 = 0; n2 < 2; ++n2) {
            const int p = n2 * 16 + l15;
            sb[n2] = s_b2[jw + p];
            tb[n2] = t_b2[jw + p];
            #pragma unroll
            for (int m2 = 0; m2 < 2; ++m2)
                #pragma unroll
                for (int r = 0; r < 4; ++r)
                    zv[n2][m2][r] = zf2[(size_t)(brow + m2 * 16 + l4 * 4 + r) * 2048 + rl * 32 + p];
        }

        f32x4 acc2[2][2][2] = {};
        #pragma unroll
        for (int k4 = 0; k4 < 4; ++k4) {
            bf16x8 ah[2][2];
            #pragma unroll
            for (int m2 = 0; m2 < 2; ++m2) {
                const int row = m2 * 16 + l15;
                const int e = row * 128 + ((k4 * 32 + l4 * 8) ^ ((row & 7) << 3));
                ah[0][m2] = *(const bf16x8*)&Hs[e];
                ah[1][m2] = *(const bf16x8*)&Ht[e];
            }
            #pragma unroll
            for (int net = 0; net < 2; ++net)
                #pragma unroll
                for (int n2 = 0; n2 < 2; ++n2) {
                    const int n = jw + n2 * 16 + l15;
                    const bf16x8 w = *(const bf16x8*)&W2T[net][(size_t)n * 128 + k4 * 32 + l4 * 8];
                    #pragma unroll
                    for (int m2 = 0; m2 < 2; ++m2)
                        acc2[net][m2][n2] = __builtin_amdgcn_mfma_f32_16x16x32_bf16(
                            ah[net][m2], w, acc2[net][m2][n2], 0, 0, 0);
                }
        }

        #pragma unroll
        for (int n2 = 0; n2 < 2; ++n2) {
            const int p = n2 * 16 + l15;
            #pragma unroll
            for (int m2 = 0; m2 < 2; ++m2)
                #pragma unroll
                for (int r = 0; r < 4; ++r) {
                    const float sv = acc2[0][m2][n2][r] + sb[n2];
                    const float tv = acc2[1][m2][n2][r] + tb[n2];
                    const float2 zp = zv[n2][m2][r];
                    const float za = evenA ? zp.x : zp.y;
                    const float zb = evenA ? zp.y : zp.x;
                    const float fb = (zb - tv) * __expf(-sv);
                    float2 fv;
                    if (evenA) { fv.x = za; fv.y = fb; }
                    else       { fv.x = fb; fv.y = za; }
                    ff2[(size_t)(brow + m2 * 16 + l4 * 4 + r) * 2048 + rl * 32 + p] = fv;
                    dsum[m2][r] += sv;
                }
        }
    }

    // ---------------- d reduction ----------------
    #pragma unroll
    for (int m2 = 0; m2 < 2; ++m2)
        #pragma unroll
        for (int r = 0; r < 4; ++r) {
            float v = dsum[m2][r];
            v += __shfl_xor(v, 1);
            v += __shfl_xor(v, 2);
            v += __shfl_xor(v, 4);
            v += __shfl_xor(v, 8);
            if (l15 == 0) Dred[wave * 32 + m2 * 16 + l4 * 4 + r] = v;
        }
    __syncthreads();
    if (tid < BM)
        d_vec[brow + tid] = Dred[tid] + Dred[32 + tid] + Dred[64 + tid] + Dred[96 + tid];
}

extern "C" void kernel_launch(void* const* d_in, const int* in_sizes, int n_in,
                              void* d_out, int out_size, void* d_ws, size_t ws_size,
                              hipStream_t stream) {
    const float* z   = (const float*)d_in[0];
    const float* sW0 = (const float*)d_in[1];
    const float* sW1 = (const float*)d_in[2];
    const float* sW2 = (const float*)d_in[3];
    const float* sb2 = (const float*)d_in[4];
    const float* tW0 = (const float*)d_in[5];
    const float* tW1 = (const float*)d_in[6];
    const float* tW2 = (const float*)d_in[7];
    const float* tb2 = (const float*)d_in[8];

    float* fout = (float*)d_out;
    float* dvec = fout + (size_t)BATCH * NSITES;
    unsigned short* ws = (unsigned short*)d_ws;

    hipLaunchKernelGGL(conv_w, dim3(512), dim3(256), 0, stream,
                       sW0, sW1, sW2, tW0, tW1, tW2, ws);
    hipLaunchKernelGGL(coupling_main, dim3(BATCH / BM), dim3(256), 0, stream,
                       z, sb2, tb2, ws, fout, dvec);
}

// Round 4
// 343.762 us; speedup vs baseline: 1.4419x; 1.4419x over previous
//
#include <hip/hip_runtime.h>
#include <hip/hip_bf16.h>

#define BATCH  16384
#define NSITES 4096
#define SLOPE  0.2f
#define BM     64

typedef __attribute__((ext_vector_type(8))) short bf16x8;
typedef __attribute__((ext_vector_type(4))) float f32x4;

// ws layout (bf16 element offsets), all matrices stored TRANSPOSED as [N][K].
// s/t blocks are contiguous so a unified column index g in [0,256) (g>>7 = net)
// addresses W0T/W1T as one matrix.
#define OFF_SW0T 0         // [128][2048]  (t at +262144 = 128*2048)
#define OFF_TW0T 262144
#define OFF_SW1T 524288    // [128][128]   (t at +16384 = 128*128)
#define OFF_TW1T 540672
#define OFF_SW2T 557056    // [2048][128]
#define OFF_TW2T 819200

__device__ __forceinline__ unsigned short f2bf(float f) {
    unsigned int u = __float_as_uint(f);
    u += 0x7FFFu + ((u >> 16) & 1u);   // round-to-nearest-even
    return (unsigned short)(u >> 16);
}

__global__ void conv_w(const float* __restrict__ sW0, const float* __restrict__ sW1,
                       const float* __restrict__ sW2, const float* __restrict__ tW0,
                       const float* __restrict__ tW1, const float* __restrict__ tW2,
                       unsigned short* __restrict__ ws) {
    const int total = 262144 + 16384 + 262144;
    for (int i = blockIdx.x * blockDim.x + threadIdx.x; i < total;
         i += gridDim.x * blockDim.x) {
        if (i < 262144) {                    // W0 [2048][128] -> [128][2048]
            int k = i >> 7, n = i & 127;
            ws[OFF_SW0T + n * 2048 + k] = f2bf(sW0[i]);
            ws[OFF_TW0T + n * 2048 + k] = f2bf(tW0[i]);
        } else if (i < 262144 + 16384) {     // W1 [128][128] -> [128][128]^T
            int j = i - 262144;
            int k = j >> 7, n = j & 127;
            ws[OFF_SW1T + n * 128 + k] = f2bf(sW1[j]);
            ws[OFF_TW1T + n * 128 + k] = f2bf(tW1[j]);
        } else {                             // W2 [128][2048] -> [2048][128]
            int j = i - (262144 + 16384);
            int k = j >> 11, n = j & 2047;
            ws[OFF_SW2T + n * 128 + k] = f2bf(sW2[j]);
            ws[OFF_TW2T + n * 128 + k] = f2bf(tW2[j]);
        }
    }
}

__global__ __launch_bounds__(512, 2) void coupling_main(
    const float* __restrict__ z,
    const float* __restrict__ s_b2,
    const float* __restrict__ t_b2,
    const unsigned short* __restrict__ ws,
    float* __restrict__ f_out,
    float* __restrict__ d_vec) {

    // flat LDS: Az [64][64] u16 (8 KB) | HA [64][256] u16 (32 KB) | HB (32 KB)
    // Dred [8][32] f32 overlays the Az region (Az dead after layer 0).
    __shared__ __align__(16) unsigned char LDSbuf[73728];
    unsigned short* Az = (unsigned short*)LDSbuf;
    unsigned short* HA = (unsigned short*)(LDSbuf + 8192);
    unsigned short* HB = (unsigned short*)(LDSbuf + 40960);
    float* Dred = (float*)LDSbuf;

    const int tid  = threadIdx.x;
    const int wave = tid >> 6;
    const int lane = tid & 63;
    const int l15  = lane & 15;
    const int l4   = lane >> 4;
    const int wm   = wave >> 2;   // m-half (rows wm*32 .. +32)
    const int wn   = wave & 3;    // n-quarter
    const int brow = blockIdx.x * BM;

    const float2* __restrict__ zf2 = (const float2*)z;
    const float4* __restrict__ zf4 = (const float4*)z;
    float2* __restrict__ ff2 = (float2*)f_out;

    // staging constants: thread covers rows srow0+16*i (i=0..3), float4 col scol
    const int srow0 = tid >> 5;      // 0..15
    const int scol  = tid & 31;      // float4 col within 128-float chunk
    const int spar  = scol >> 4;     // parity of this float4's lattice row (2c even)

    // ---------------- layer 0: h0 = leaky(z_a @ W0), unified g in [0,256) ----------------
    f32x4 acc0[2][4] = {};   // [m][n2]

    // prologue: stage chunk 0
    {
        #pragma unroll
        for (int i = 0; i < 4; ++i) {
            const int row = srow0 + 16 * i;
            const float4 v = zf4[(size_t)(brow + row) * 1024 + scol];
            const float a0 = spar ? v.y : v.x;
            const float a1 = spar ? v.w : v.z;
            const unsigned int pk = (unsigned int)f2bf(a0) | ((unsigned int)f2bf(a1) << 16);
            ((unsigned int*)Az)[row * 32 + (scol ^ ((row & 7) << 2))] = pk;
        }
    }
    __syncthreads();

    #pragma unroll 1
    for (int c = 0; c < 32; ++c) {
        // T14: issue next chunk's global loads first
        float4 pre[4];
        if (c < 31) {
            #pragma unroll
            for (int i = 0; i < 4; ++i) {
                const int row = srow0 + 16 * i;
                pre[i] = zf4[(size_t)(brow + row) * 1024 + (c + 1) * 32 + scol];
            }
        }

        // compute current chunk
        bf16x8 af[2][2];
        #pragma unroll
        for (int m = 0; m < 2; ++m)
            #pragma unroll
            for (int k2 = 0; k2 < 2; ++k2) {
                const int row = wm * 32 + m * 16 + l15;
                af[m][k2] = *(const bf16x8*)&Az[row * 64 +
                               ((k2 * 32 + l4 * 8) ^ ((row & 7) << 3))];
            }
        #pragma unroll
        for (int n2 = 0; n2 < 4; ++n2) {
            const size_t wb = (size_t)(wn * 64 + n2 * 16 + l15) * 2048 + c * 64 + l4 * 8;
            #pragma unroll
            for (int k2 = 0; k2 < 2; ++k2) {
                const bf16x8 w = *(const bf16x8*)&ws[OFF_SW0T + wb + k2 * 32];
                #pragma unroll
                for (int m = 0; m < 2; ++m)
                    acc0[m][n2] = __builtin_amdgcn_mfma_f32_16x16x32_bf16(
                        af[m][k2], w, acc0[m][n2], 0, 0, 0);
            }
        }
        __syncthreads();
        if (c < 31) {
            #pragma unroll
            for (int i = 0; i < 4; ++i) {
                const int row = srow0 + 16 * i;
                const float a0 = spar ? pre[i].y : pre[i].x;
                const float a1 = spar ? pre[i].w : pre[i].z;
                const unsigned int pk = (unsigned int)f2bf(a0) | ((unsigned int)f2bf(a1) << 16);
                ((unsigned int*)Az)[row * 32 + (scol ^ ((row & 7) << 2))] = pk;
            }
        }
        __syncthreads();
    }

    // leaky relu, h0 -> HA (swizzled)
    #pragma unroll
    for (int m = 0; m < 2; ++m)
        #pragma unroll
        for (int n2 = 0; n2 < 4; ++n2)
            #pragma unroll
            for (int r = 0; r < 4; ++r) {
                float v = acc0[m][n2][r];
                v = v > 0.0f ? v : SLOPE * v;
                const int row = wm * 32 + m * 16 + l4 * 4 + r;
                const int col = wn * 64 + n2 * 16 + l15;
                HA[row * 256 + (col ^ ((row & 7) << 3))] = f2bf(v);
            }
    __syncthreads();

    // ---------------- layer 1: h1 = leaky(h0 @ W1) ----------------
    f32x4 acc1[2][4] = {};
    const int net1 = wn >> 1;    // this wave's g-cols all belong to one net
    #pragma unroll
    for (int k4 = 0; k4 < 4; ++k4) {
        bf16x8 ah[2];
        #pragma unroll
        for (int m = 0; m < 2; ++m) {
            const int row = wm * 32 + m * 16 + l15;
            ah[m] = *(const bf16x8*)&HA[row * 256 +
                       ((net1 * 128 + k4 * 32 + l4 * 8) ^ ((row & 7) << 3))];
        }
        #pragma unroll
        for (int n2 = 0; n2 < 4; ++n2) {
            const bf16x8 w = *(const bf16x8*)&ws[OFF_SW1T +
                (size_t)(wn * 64 + n2 * 16 + l15) * 128 + k4 * 32 + l4 * 8];
            #pragma unroll
            for (int m = 0; m < 2; ++m)
                acc1[m][n2] = __builtin_amdgcn_mfma_f32_16x16x32_bf16(
                    ah[m], w, acc1[m][n2], 0, 0, 0);
        }
    }
    #pragma unroll
    for (int m = 0; m < 2; ++m)
        #pragma unroll
        for (int n2 = 0; n2 < 4; ++n2)
            #pragma unroll
            for (int r = 0; r < 4; ++r) {
                float v = acc1[m][n2][r];
                v = v > 0.0f ? v : SLOPE * v;
                const int row = wm * 32 + m * 16 + l4 * 4 + r;
                const int col = wn * 64 + n2 * 16 + l15;
                HB[row * 256 + (col ^ ((row & 7) << 3))] = f2bf(v);
            }
    __syncthreads();

    // ---------------- layer 2 + epilogue: 16 iters, wave covers 32 out-cols ----------------
    float dsum[2][4] = {};
    #pragma unroll 1
    for (int c2 = 0; c2 < 16; ++c2) {
        const int rl = c2 * 4 + wn;          // lattice row (wave's 32 cols = this row)
        const int evenA = 1 - (rl & 1);

        // hoisted epilogue loads (overlap the MFMA block below)
        float sbv[2], tbv[2];
        float2 zv[2][2][4];
        #pragma unroll
        for (int n2 = 0; n2 < 2; ++n2) {
            const int j = rl * 32 + n2 * 16 + l15;
            sbv[n2] = s_b2[j];
            tbv[n2] = t_b2[j];
            #pragma unroll
            for (int m = 0; m < 2; ++m)
                #pragma unroll
                for (int r = 0; r < 4; ++r)
                    zv[n2][m][r] = zf2[(size_t)(brow + wm * 32 + m * 16 + l4 * 4 + r) * 2048 + j];
        }

        f32x4 acc2[2][2][2] = {};   // [net][m][n2]
        #pragma unroll
        for (int k4 = 0; k4 < 4; ++k4) {
            bf16x8 ahs[2], aht[2];
            #pragma unroll
            for (int m = 0; m < 2; ++m) {
                const int row = wm * 32 + m * 16 + l15;
                const int kc = k4 * 32 + l4 * 8;
                ahs[m] = *(const bf16x8*)&HB[row * 256 + (kc ^ ((row & 7) << 3))];
                aht[m] = *(const bf16x8*)&HB[row * 256 + ((128 + kc) ^ ((row & 7) << 3))];
            }
            #pragma unroll
            for (int n2 = 0; n2 < 2; ++n2) {
                const int j = rl * 32 + n2 * 16 + l15;
                const bf16x8 wsf = *(const bf16x8*)&ws[OFF_SW2T + (size_t)j * 128 + k4 * 32 + l4 * 8];
                const bf16x8 wtf = *(const bf16x8*)&ws[OFF_TW2T + (size_t)j * 128 + k4 * 32 + l4 * 8];
                #pragma unroll
                for (int m = 0; m < 2; ++m) {
                    acc2[0][m][n2] = __builtin_amdgcn_mfma_f32_16x16x32_bf16(
                        ahs[m], wsf, acc2[0][m][n2], 0, 0, 0);
                    acc2[1][m][n2] = __builtin_amdgcn_mfma_f32_16x16x32_bf16(
                        aht[m], wtf, acc2[1][m][n2], 0, 0, 0);
                }
            }
        }

        #pragma unroll
        for (int n2 = 0; n2 < 2; ++n2) {
            #pragma unroll
            for (int m = 0; m < 2; ++m)
                #pragma unroll
                for (int r = 0; r < 4; ++r) {
                    const float sv = acc2[0][m][n2][r] + sbv[n2];
                    const float tv = acc2[1][m][n2][r] + tbv[n2];
                    const float2 zp = zv[n2][m][r];
                    const float za = evenA ? zp.x : zp.y;
                    const float zb = evenA ? zp.y : zp.x;
                    const float fb = (zb - tv) * __expf(-sv);
                    float2 fv;
                    if (evenA) { fv.x = za; fv.y = fb; }
                    else       { fv.x = fb; fv.y = za; }
                    ff2[(size_t)(brow + wm * 32 + m * 16 + l4 * 4 + r) * 2048
                        + rl * 32 + n2 * 16 + l15] = fv;
                    dsum[m][r] += sv;
                }
        }
    }

    // ---------------- d reduction ----------------
    #pragma unroll
    for (int m = 0; m < 2; ++m)
        #pragma unroll
        for (int r = 0; r < 4; ++r) {
            float v = dsum[m][r];
            v += __shfl_xor(v, 1);
            v += __shfl_xor(v, 2);
            v += __shfl_xor(v, 4);
            v += __shfl_xor(v, 8);
            if (l15 == 0) Dred[wave * 32 + m * 16 + l4 * 4 + r] = v;
        }
    __syncthreads();
    if (tid < BM) {
        const int wmr = tid >> 5, rowin = tid & 31;
        d_vec[brow + tid] = Dred[(wmr * 4 + 0) * 32 + rowin]
                          + Dred[(wmr * 4 + 1) * 32 + rowin]
                          + Dred[(wmr * 4 + 2) * 32 + rowin]
                          + Dred[(wmr * 4 + 3) * 32 + rowin];
    }
}

extern "C" void kernel_launch(void* const* d_in, const int* in_sizes, int n_in,
                              void* d_out, int out_size, void* d_ws, size_t ws_size,
                              hipStream_t stream) {
    const float* z   = (const float*)d_in[0];
    const float* sW0 = (const float*)d_in[1];
    const float* sW1 = (const float*)d_in[2];
    const float* sW2 = (const float*)d_in[3];
    const float* sb2 = (const float*)d_in[4];
    const float* tW0 = (const float*)d_in[5];
    const float* tW1 = (const float*)d_in[6];
    const float* tW2 = (const float*)d_in[7];
    const float* tb2 = (const float*)d_in[8];

    float* fout = (float*)d_out;
    float* dvec = fout + (size_t)BATCH * NSITES;
    unsigned short* ws = (unsigned short*)d_ws;

    hipLaunchKernelGGL(conv_w, dim3(512), dim3(256), 0, stream,
                       sW0, sW1, sW2, tW0, tW1, tW2, ws);
    hipLaunchKernelGGL(coupling_main, dim3(BATCH / BM), dim3(512), 0, stream,
                       z, sb2, tb2, ws, fout, dvec);
}

// Round 5
// 318.863 us; speedup vs baseline: 1.5545x; 1.0781x over previous
//
#include <hip/hip_runtime.h>
#include <hip/hip_bf16.h>

#define BATCH  16384
#define SLOPE  0.2f
#define BM     64

typedef __attribute__((ext_vector_type(8))) short bf16x8;
typedef __attribute__((ext_vector_type(4))) float f32x4;

// ws layout (bf16 element offsets), weights TRANSPOSED as [N][K]; s/t contiguous.
#define OFF_SW0T 0         // [128][2048]
#define OFF_TW0T 262144
#define OFF_SW1T 524288    // [128][128]
#define OFF_TW1T 540672
#define OFF_SW2T 557056    // [2048][128]
#define OFF_TW2T 819200

__device__ __forceinline__ unsigned short f2bf(float f) {
    unsigned int u = __float_as_uint(f);
    u += 0x7FFFu + ((u >> 16) & 1u);   // round-to-nearest-even
    return (unsigned short)(u >> 16);
}

__global__ void conv_w(const float* __restrict__ sW0, const float* __restrict__ sW1,
                       const float* __restrict__ sW2, const float* __restrict__ tW0,
                       const float* __restrict__ tW1, const float* __restrict__ tW2,
                       unsigned short* __restrict__ ws) {
    const int total = 262144 + 16384 + 262144;
    for (int i = blockIdx.x * blockDim.x + threadIdx.x; i < total;
         i += gridDim.x * blockDim.x) {
        if (i < 262144) {                    // W0 [2048][128] -> [128][2048]
            int k = i >> 7, n = i & 127;
            ws[OFF_SW0T + n * 2048 + k] = f2bf(sW0[i]);
            ws[OFF_TW0T + n * 2048 + k] = f2bf(tW0[i]);
        } else if (i < 262144 + 16384) {     // W1 [128][128] -> transpose
            int j = i - 262144;
            int k = j >> 7, n = j & 127;
            ws[OFF_SW1T + n * 128 + k] = f2bf(sW1[j]);
            ws[OFF_TW1T + n * 128 + k] = f2bf(tW1[j]);
        } else {                             // W2 [128][2048] -> [2048][128]
            int j = i - (262144 + 16384);
            int k = j >> 11, n = j & 2047;
            ws[OFF_SW2T + n * 128 + k] = f2bf(sW2[j]);
            ws[OFF_TW2T + n * 128 + k] = f2bf(tW2[j]);
        }
    }
}

// z_a -> bf16, pre-swizzled (octet o at position o ^ (b&7)), stored in the tail
// 4KB of f-row b: bytes [b*16384 + 12288, b*16384 + 16384). Race-free: only row
// b's own block reads it (layer 0) before that block writes f row b (epilogue).
__global__ void conv_z(const float* __restrict__ z, char* __restrict__ fbytes) {
    const int total = BATCH * 256;
    for (int idx = blockIdx.x * blockDim.x + threadIdx.x; idx < total;
         idx += gridDim.x * blockDim.x) {
        const int b  = idx >> 8;
        const int o  = idx & 255;            // A-octet index (8 A-sites)
        const int rl = o >> 2;               // lattice row (4 octets per row)
        const int par = rl & 1;
        const float4* src = (const float4*)(z + (size_t)b * 4096 + rl * 64 + (o & 3) * 16);
        const float4 v0 = src[0], v1 = src[1], v2 = src[2], v3 = src[3];
        union { bf16x8 v; __hip_bfloat162 h[4]; } u;
        u.h[0] = __float22bfloat162_rn(par ? make_float2(v0.y, v0.w) : make_float2(v0.x, v0.z));
        u.h[1] = __float22bfloat162_rn(par ? make_float2(v1.y, v1.w) : make_float2(v1.x, v1.z));
        u.h[2] = __float22bfloat162_rn(par ? make_float2(v2.y, v2.w) : make_float2(v2.x, v2.z));
        u.h[3] = __float22bfloat162_rn(par ? make_float2(v3.y, v3.w) : make_float2(v3.x, v3.z));
        const int oSwz = o ^ (b & 7);
        *(bf16x8*)(fbytes + (size_t)b * 16384 + 12288 + (size_t)oSwz * 16) = u.v;
    }
}

__global__ __launch_bounds__(512, 2) void coupling_main(
    const float* __restrict__ z,
    const float* __restrict__ s_b2,
    const float* __restrict__ t_b2,
    const unsigned short* __restrict__ ws,
    float* __restrict__ f_out,
    float* __restrict__ d_vec) {

    // LDS pool: [0,16K) Az dbuf (layer0) / Sst f32 [64][132] (layer2, overlays Az+HA)
    //           [16K,48K) HA | [48K,80K) HB
    __shared__ __align__(16) unsigned char LDSbuf[81920];
    unsigned short* HA = (unsigned short*)(LDSbuf + 16384);
    unsigned short* HB = (unsigned short*)(LDSbuf + 49152);
    float* Sst = (float*)LDSbuf;

    const int tid  = threadIdx.x;
    const int wave = tid >> 6;
    const int lane = tid & 63;
    const int l15  = lane & 15;
    const int l4   = lane >> 4;
    const int wm   = wave >> 2;   // layer0/1 m-half
    const int wn   = wave & 3;    // layer0/1 n-quarter
    const int brow = blockIdx.x * BM;

    const char* fbytes = (const char*)f_out;

    // ---------------- layer 0: h0 = leaky(z_a @ W0), DMA-staged A ----------------
    auto stage = [&](int buf, int c) {
        const char* g = fbytes + (size_t)(brow + wave * 8 + (lane >> 3)) * 16384 + 12288
                        + (size_t)(c * 64 + (lane & 7) * 8) * 2;
        void* l = LDSbuf + buf * 8192 + wave * 1024;
        __builtin_amdgcn_global_load_lds(
            (const __attribute__((address_space(1))) unsigned int*)g,
            (__attribute__((address_space(3))) unsigned int*)l, 16, 0, 0);
    };

    stage(0, 0);
    __syncthreads();   // compiler emits vmcnt(0) drain before barrier

    f32x4 acc0[2][4] = {};   // [m][n2]
    int cur = 0;
    #pragma unroll 1
    for (int c = 0; c < 32; ++c) {
        if (c < 31) stage(cur ^ 1, c + 1);
        const char* Az = (const char*)(LDSbuf + cur * 8192);
        bf16x8 af[2][2];
        #pragma unroll
        for (int m = 0; m < 2; ++m)
            #pragma unroll
            for (int k2 = 0; k2 < 2; ++k2) {
                const int row = wm * 32 + m * 16 + l15;
                af[m][k2] = *(const bf16x8*)(Az + row * 128 +
                              (((k2 * 32 + l4 * 8) * 2) ^ ((row & 7) << 4)));
            }
        #pragma unroll
        for (int n2 = 0; n2 < 4; ++n2) {
            const size_t wb = (size_t)(wn * 64 + n2 * 16 + l15) * 2048 + c * 64 + l4 * 8;
            #pragma unroll
            for (int k2 = 0; k2 < 2; ++k2) {
                const bf16x8 w = *(const bf16x8*)&ws[OFF_SW0T + wb + k2 * 32];
                #pragma unroll
                for (int m = 0; m < 2; ++m)
                    acc0[m][n2] = __builtin_amdgcn_mfma_f32_16x16x32_bf16(
                        af[m][k2], w, acc0[m][n2], 0, 0, 0);
            }
        }
        __syncthreads();
        cur ^= 1;
    }

    // leaky relu, h0 -> HA (swizzled)
    #pragma unroll
    for (int m = 0; m < 2; ++m)
        #pragma unroll
        for (int n2 = 0; n2 < 4; ++n2)
            #pragma unroll
            for (int r = 0; r < 4; ++r) {
                float v = acc0[m][n2][r];
                v = v > 0.0f ? v : SLOPE * v;
                const int row = wm * 32 + m * 16 + l4 * 4 + r;
                const int col = wn * 64 + n2 * 16 + l15;
                HA[row * 256 + (col ^ ((row & 7) << 3))] = f2bf(v);
            }
    __syncthreads();

    // ---------------- layer 1: h1 = leaky(h0 @ W1) ----------------
    f32x4 acc1[2][4] = {};
    const int net1 = wn >> 1;
    #pragma unroll
    for (int k4 = 0; k4 < 4; ++k4) {
        bf16x8 ahv[2];
        #pragma unroll
        for (int m = 0; m < 2; ++m) {
            const int row = wm * 32 + m * 16 + l15;
            ahv[m] = *(const bf16x8*)&HA[row * 256 +
                       ((net1 * 128 + k4 * 32 + l4 * 8) ^ ((row & 7) << 3))];
        }
        #pragma unroll
        for (int n2 = 0; n2 < 4; ++n2) {
            const bf16x8 w = *(const bf16x8*)&ws[OFF_SW1T +
                (size_t)(wn * 64 + n2 * 16 + l15) * 128 + k4 * 32 + l4 * 8];
            #pragma unroll
            for (int m = 0; m < 2; ++m)
                acc1[m][n2] = __builtin_amdgcn_mfma_f32_16x16x32_bf16(
                    ahv[m], w, acc1[m][n2], 0, 0, 0);
        }
    }
    #pragma unroll
    for (int m = 0; m < 2; ++m)
        #pragma unroll
        for (int n2 = 0; n2 < 4; ++n2)
            #pragma unroll
            for (int r = 0; r < 4; ++r) {
                float v = acc1[m][n2][r];
                v = v > 0.0f ? v : SLOPE * v;
                const int row = wm * 32 + m * 16 + l4 * 4 + r;
                const int col = wn * 64 + n2 * 16 + l15;
                HB[row * 256 + (col ^ ((row & 7) << 3))] = f2bf(v);
            }
    __syncthreads();

    // ---------------- layer 2 + epilogue: 32 n-chunks of 64 pairs ----------------
    // wave -> (net, nq): computes 64 rows x 16 pair-cols of net's output.
    const int net = wave >> 2;
    const int nq  = wave & 3;

    // hoist A-fragments (chunk-invariant): 16 x bf16x8 = 64 VGPR
    bf16x8 ah[4][4];   // [m][k4]
    #pragma unroll
    for (int m = 0; m < 4; ++m)
        #pragma unroll
        for (int k4 = 0; k4 < 4; ++k4) {
            const int row = m * 16 + l15;
            ah[m][k4] = *(const bf16x8*)&HB[row * 256 +
                          ((net * 128 + k4 * 32 + l4 * 8) ^ ((row & 7) << 3))];
        }

    const int erow = tid >> 3;          // epilogue row 0..63
    const int eq   = tid & 7;           // epilogue col-octet (16 f-cols)
    const int par2 = (eq >> 2) & 1;     // lattice-row parity of this thread's pairs
    float dsum = 0.0f;

    #pragma unroll 1
    for (int c2 = 0; c2 < 32; ++c2) {
        const int jp = c2 * 64 + nq * 16 + l15;        // global pair index
        const float bia = net ? t_b2[jp] : s_b2[jp];
        f32x4 acc2[4] = {};
        #pragma unroll
        for (int k4 = 0; k4 < 4; ++k4) {
            const bf16x8 w = *(const bf16x8*)&ws[OFF_SW2T + (size_t)net * 262144 +
                                                 (size_t)jp * 128 + k4 * 32 + l4 * 8];
            #pragma unroll
            for (int m = 0; m < 4; ++m)
                acc2[m] = __builtin_amdgcn_mfma_f32_16x16x32_bf16(
                    ah[m][k4], w, acc2[m], 0, 0, 0);
        }
        #pragma unroll
        for (int m = 0; m < 4; ++m)
            #pragma unroll
            for (int r = 0; r < 4; ++r)
                Sst[(m * 16 + l4 * 4 + r) * 132 + net * 64 + nq * 16 + l15] =
                    acc2[m][r] + bia;
        __syncthreads();

        // epilogue: fully contiguous float4 I/O, 64B per thread
        const float4* zq = (const float4*)(z     + (size_t)(brow + erow) * 4096 + c2 * 128 + eq * 16);
        float4*       fq = (float4*)      (f_out + (size_t)(brow + erow) * 4096 + c2 * 128 + eq * 16);
        const float4 sv0 = *(const float4*)&Sst[erow * 132 + eq * 8];
        const float4 sv1 = *(const float4*)&Sst[erow * 132 + eq * 8 + 4];
        const float4 tv0 = *(const float4*)&Sst[erow * 132 + 64 + eq * 8];
        const float4 tv1 = *(const float4*)&Sst[erow * 132 + 64 + eq * 8 + 4];
        const float sarr[8] = {sv0.x, sv0.y, sv0.z, sv0.w, sv1.x, sv1.y, sv1.z, sv1.w};
        const float tarr[8] = {tv0.x, tv0.y, tv0.z, tv0.w, tv1.x, tv1.y, tv1.z, tv1.w};
        #pragma unroll
        for (int i = 0; i < 4; ++i) {
            const float4 zv = zq[i];
            const float s0 = sarr[2 * i], s1 = sarr[2 * i + 1];
            const float t0 = tarr[2 * i], t1 = tarr[2 * i + 1];
            const float za0 = par2 ? zv.y : zv.x;
            const float zb0 = par2 ? zv.x : zv.y;
            const float za1 = par2 ? zv.w : zv.z;
            const float zb1 = par2 ? zv.z : zv.w;
            const float fb0 = (zb0 - t0) * __expf(-s0);
            const float fb1 = (zb1 - t1) * __expf(-s1);
            float4 fv;
            if (par2) { fv.x = fb0; fv.y = za0; fv.z = fb1; fv.w = za1; }
            else      { fv.x = za0; fv.y = fb0; fv.z = za1; fv.w = fb1; }
            fq[i] = fv;
            dsum += s0 + s1;
        }
        __syncthreads();
    }

    // ---------------- d reduction: 8 threads per row, in-wave ----------------
    dsum += __shfl_xor(dsum, 1);
    dsum += __shfl_xor(dsum, 2);
    dsum += __shfl_xor(dsum, 4);
    if (eq == 0) d_vec[brow + erow] = dsum;
}

extern "C" void kernel_launch(void* const* d_in, const int* in_sizes, int n_in,
                              void* d_out, int out_size, void* d_ws, size_t ws_size,
                              hipStream_t stream) {
    const float* z   = (const float*)d_in[0];
    const float* sW0 = (const float*)d_in[1];
    const float* sW1 = (const float*)d_in[2];
    const float* sW2 = (const float*)d_in[3];
    const float* sb2 = (const float*)d_in[4];
    const float* tW0 = (const float*)d_in[5];
    const float* tW1 = (const float*)d_in[6];
    const float* tW2 = (const float*)d_in[7];
    const float* tb2 = (const float*)d_in[8];

    float* fout = (float*)d_out;
    float* dvec = fout + (size_t)BATCH * 4096;
    unsigned short* ws = (unsigned short*)d_ws;

    hipLaunchKernelGGL(conv_w, dim3(512), dim3(256), 0, stream,
                       sW0, sW1, sW2, tW0, tW1, tW2, ws);
    hipLaunchKernelGGL(conv_z, dim3(4096), dim3(256), 0, stream,
                       z, (char*)d_out);
    hipLaunchKernelGGL(coupling_main, dim3(BATCH / BM), dim3(512), 0, stream,
                       z, sb2, tb2, ws, fout, dvec);
}

// Round 7
// 291.793 us; speedup vs baseline: 1.6987x; 1.0928x over previous
//
#include <hip/hip_runtime.h>
#include <hip/hip_bf16.h>

#define BATCH  16384
#define SLOPE  0.2f
#define BM     32

typedef __attribute__((ext_vector_type(8))) short bf16x8;
typedef __attribute__((ext_vector_type(4))) float f32x4;

// ws layout (bf16 element offsets), weights TRANSPOSED as [N][K]; s/t contiguous.
#define OFF_SW0T 0         // [128][2048]
#define OFF_TW0T 262144
#define OFF_SW1T 524288    // [128][128]
#define OFF_TW1T 540672
#define OFF_SW2T 557056    // [2048][128]
#define OFF_TW2T 819200

__device__ __forceinline__ unsigned short f2bf(float f) {
    unsigned int u = __float_as_uint(f);
    u += 0x7FFFu + ((u >> 16) & 1u);   // round-to-nearest-even
    return (unsigned short)(u >> 16);
}

__global__ void conv_w(const float* __restrict__ sW0, const float* __restrict__ sW1,
                       const float* __restrict__ sW2, const float* __restrict__ tW0,
                       const float* __restrict__ tW1, const float* __restrict__ tW2,
                       unsigned short* __restrict__ ws) {
    const int total = 262144 + 16384 + 262144;
    for (int i = blockIdx.x * blockDim.x + threadIdx.x; i < total;
         i += gridDim.x * blockDim.x) {
        if (i < 262144) {                    // W0 [2048][128] -> [128][2048]
            int k = i >> 7, n = i & 127;
            ws[OFF_SW0T + n * 2048 + k] = f2bf(sW0[i]);
            ws[OFF_TW0T + n * 2048 + k] = f2bf(tW0[i]);
        } else if (i < 262144 + 16384) {     // W1 [128][128] -> transpose
            int j = i - 262144;
            int k = j >> 7, n = j & 127;
            ws[OFF_SW1T + n * 128 + k] = f2bf(sW1[j]);
            ws[OFF_TW1T + n * 128 + k] = f2bf(tW1[j]);
        } else {                             // W2 [128][2048] -> [2048][128]
            int j = i - (262144 + 16384);
            int k = j >> 11, n = j & 2047;
            ws[OFF_SW2T + n * 128 + k] = f2bf(sW2[j]);
            ws[OFF_TW2T + n * 128 + k] = f2bf(tW2[j]);
        }
    }
}

// z_a -> bf16, pre-swizzled (octet o stored at position o ^ (b&7)), in the tail
// 4KB of f-row b. Race-free: only row b's own block reads it (layer 0) before
// that block overwrites it (epilogue chunks 24-31).
__global__ void conv_z(const float* __restrict__ z, char* __restrict__ fbytes) {
    const int total = BATCH * 256;
    for (int idx = blockIdx.x * blockDim.x + threadIdx.x; idx < total;
         idx += gridDim.x * blockDim.x) {
        const int b  = idx >> 8;
        const int o  = idx & 255;            // A-octet index (8 A-sites)
        const int rl = o >> 2;               // lattice row (4 octets per row)
        const int par = rl & 1;
        const float4* src = (const float4*)(z + (size_t)b * 4096 + rl * 64 + (o & 3) * 16);
        const float4 v0 = src[0], v1 = src[1], v2 = src[2], v3 = src[3];
        union { bf16x8 v; __hip_bfloat162 h[4]; } u;
        u.h[0] = __float22bfloat162_rn(par ? make_float2(v0.y, v0.w) : make_float2(v0.x, v0.z));
        u.h[1] = __float22bfloat162_rn(par ? make_float2(v1.y, v1.w) : make_float2(v1.x, v1.z));
        u.h[2] = __float22bfloat162_rn(par ? make_float2(v2.y, v2.w) : make_float2(v2.x, v2.z));
        u.h[3] = __float22bfloat162_rn(par ? make_float2(v3.y, v3.w) : make_float2(v3.x, v3.z));
        const int oSwz = o ^ (b & 7);
        *(bf16x8*)(fbytes + (size_t)b * 16384 + 12288 + (size_t)oSwz * 16) = u.v;
    }
}

__global__ __launch_bounds__(256, 2) void coupling_main(
    const float* __restrict__ z,
    const float* __restrict__ s_b2,
    const float* __restrict__ t_b2,
    const unsigned short* __restrict__ ws,
    float* __restrict__ f_out,
    float* __restrict__ d_vec) {

    // LDS: [0,16K) Az: 2 granules x 2 chunks x [32 rows][128B]; Dred overlays later
    //      [16K,32K) HA [32][256] u16 swz | [32K,48K) HB
    __shared__ __align__(16) unsigned char LDSbuf[49152];
    unsigned short* HA = (unsigned short*)(LDSbuf + 16384);
    unsigned short* HB = (unsigned short*)(LDSbuf + 32768);
    float* Dred = (float*)LDSbuf;

    const int tid  = threadIdx.x;
    const int wave = tid >> 6;
    const int lane = tid & 63;
    const int l15  = lane & 15;
    const int l4   = lane >> 4;
    const int brow = blockIdx.x * BM;

    const char* fbytes = (const char*)f_out;
    const float2* __restrict__ zf2 = (const float2*)z;
    float2* __restrict__ ff2 = (float2*)f_out;

    // stage chunk c (64 A-cols = 128B/row, 32 rows) at LDS byte offset `off`
    auto stage = [&](int off, int c) {
        const char* g = fbytes + (size_t)(brow + wave * 8 + (lane >> 3)) * 16384 + 12288
                        + (size_t)(c * 8 + (lane & 7)) * 16;
        void* l = LDSbuf + off + wave * 1024;
        __builtin_amdgcn_global_load_lds(
            (const __attribute__((address_space(1))) unsigned int*)g,
            (__attribute__((address_space(3))) unsigned int*)l, 16, 0, 0);
    };

    // ---------------- layer 0: h0 = leaky(z_a @ W0), unified g in [0,256) ----------------
    stage(0, 0);
    stage(4096, 1);
    __syncthreads();

    f32x4 acc0[2][4] = {};   // [m][n2]
    #pragma unroll 1
    for (int gIt = 0; gIt < 16; ++gIt) {
        const int cb = (gIt & 1) * 8192;
        if (gIt < 15) {
            const int nb = ((gIt + 1) & 1) * 8192;
            stage(nb, 2 * gIt + 2);
            stage(nb + 4096, 2 * gIt + 3);
        }
        #pragma unroll
        for (int half = 0; half < 2; ++half) {
            const int c = 2 * gIt + half;
            const char* Az = (const char*)(LDSbuf + cb + half * 4096);
            bf16x8 af[2][2];
            #pragma unroll
            for (int m = 0; m < 2; ++m)
                #pragma unroll
                for (int k2 = 0; k2 < 2; ++k2) {
                    const int row = m * 16 + l15;
                    af[m][k2] = *(const bf16x8*)(Az + row * 128 +
                                  (((k2 * 32 + l4 * 8) * 2) ^ ((row & 7) << 4)));
                }
            #pragma unroll
            for (int n2 = 0; n2 < 4; ++n2) {
                const size_t wb = (size_t)(wave * 64 + n2 * 16 + l15) * 2048 + c * 64 + l4 * 8;
                #pragma unroll
                for (int k2 = 0; k2 < 2; ++k2) {
                    const bf16x8 w = *(const bf16x8*)&ws[OFF_SW0T + wb + k2 * 32];
                    #pragma unroll
                    for (int m = 0; m < 2; ++m)
                        acc0[m][n2] = __builtin_amdgcn_mfma_f32_16x16x32_bf16(
                            af[m][k2], w, acc0[m][n2], 0, 0, 0);
                }
            }
        }
        __syncthreads();
    }

    // leaky relu, h0 -> HA (swizzled)
    #pragma unroll
    for (int m = 0; m < 2; ++m)
        #pragma unroll
        for (int n2 = 0; n2 < 4; ++n2)
            #pragma unroll
            for (int r = 0; r < 4; ++r) {
                float v = acc0[m][n2][r];
                v = v > 0.0f ? v : SLOPE * v;
                const int row = m * 16 + l4 * 4 + r;
                const int col = wave * 64 + n2 * 16 + l15;
                HA[row * 256 + (col ^ ((row & 7) << 3))] = f2bf(v);
            }
    __syncthreads();

    // ---------------- layer 1: h1 = leaky(h0 @ W1) ----------------
    f32x4 acc1[2][4] = {};
    const int net1 = wave >> 1;
    #pragma unroll
    for (int k4 = 0; k4 < 4; ++k4) {
        bf16x8 ahv[2];
        #pragma unroll
        for (int m = 0; m < 2; ++m) {
            const int row = m * 16 + l15;
            ahv[m] = *(const bf16x8*)&HA[row * 256 +
                       ((net1 * 128 + k4 * 32 + l4 * 8) ^ ((row & 7) << 3))];
        }
        #pragma unroll
        for (int n2 = 0; n2 < 4; ++n2) {
            const bf16x8 w = *(const bf16x8*)&ws[OFF_SW1T +
                (size_t)(wave * 64 + n2 * 16 + l15) * 128 + k4 * 32 + l4 * 8];
            #pragma unroll
            for (int m = 0; m < 2; ++m)
                acc1[m][n2] = __builtin_amdgcn_mfma_f32_16x16x32_bf16(
                    ahv[m], w, acc1[m][n2], 0, 0, 0);
        }
    }
    #pragma unroll
    for (int m = 0; m < 2; ++m)
        #pragma unroll
        for (int n2 = 0; n2 < 4; ++n2)
            #pragma unroll
            for (int r = 0; r < 4; ++r) {
                float v = acc1[m][n2][r];
                v = v > 0.0f ? v : SLOPE * v;
                const int row = m * 16 + l4 * 4 + r;
                const int col = wave * 64 + n2 * 16 + l15;
                HB[row * 256 + (col ^ ((row & 7) << 3))] = f2bf(v);
            }
    __syncthreads();

    // ---------------- layer 2 + epilogue: barrier-free, both nets per wave ----------------
    // wave = pair-quarter nq; its pairs in chunk c2: j = c2*64 + nq*16 + l15.
    // Lattice row of j = 2*c2 + (nq>>1) -> parity is wave-uniform: par = nq>>1.
    const int nq  = wave;
    const int par = wave >> 1;

    // hoist A-fragments once (32 x bf16x8 = 128 VGPR) — launch_bounds gives room
    bf16x8 ahs[2][4], aht[2][4];   // [m][k4]
    #pragma unroll
    for (int m = 0; m < 2; ++m)
        #pragma unroll
        for (int k4 = 0; k4 < 4; ++k4) {
            const int row = m * 16 + l15;
            const int kc = k4 * 32 + l4 * 8;
            ahs[m][k4] = *(const bf16x8*)&HB[row * 256 + (kc ^ ((row & 7) << 3))];
            aht[m][k4] = *(const bf16x8*)&HB[row * 256 + ((128 + kc) ^ ((row & 7) << 3))];
        }

    float dsum[2][4] = {};
    #pragma unroll 1
    for (int c2 = 0; c2 < 32; ++c2) {
        const int j = c2 * 64 + nq * 16 + l15;       // pair index (= zf2 index in row)
        const float sb = s_b2[j];
        const float tb = t_b2[j];

        // hoist z loads above the MFMA block
        float2 zv[2][4];
        #pragma unroll
        for (int m = 0; m < 2; ++m)
            #pragma unroll
            for (int r = 0; r < 4; ++r)
                zv[m][r] = zf2[(size_t)(brow + m * 16 + l4 * 4 + r) * 2048 + j];

        f32x4 acc2[2][2] = {};   // [net][m]
        #pragma unroll
        for (int k4 = 0; k4 < 4; ++k4) {
            const bf16x8 wsf = *(const bf16x8*)&ws[OFF_SW2T + (size_t)j * 128 + k4 * 32 + l4 * 8];
            const bf16x8 wtf = *(const bf16x8*)&ws[OFF_TW2T + (size_t)j * 128 + k4 * 32 + l4 * 8];
            #pragma unroll
            for (int m = 0; m < 2; ++m) {
                acc2[0][m] = __builtin_amdgcn_mfma_f32_16x16x32_bf16(
                    ahs[m][k4], wsf, acc2[0][m], 0, 0, 0);
                acc2[1][m] = __builtin_amdgcn_mfma_f32_16x16x32_bf16(
                    aht[m][k4], wtf, acc2[1][m], 0, 0, 0);
            }
        }

        #pragma unroll
        for (int m = 0; m < 2; ++m)
            #pragma unroll
            for (int r = 0; r < 4; ++r) {
                const float sv = acc2[0][m][r] + sb;
                const float tv = acc2[1][m][r] + tb;
                const float2 zp = zv[m][r];
                const float za = par ? zp.y : zp.x;
                const float zb = par ? zp.x : zp.y;
                const float fb = (zb - tv) * __expf(-sv);
                float2 fv;
                if (par) { fv.x = fb; fv.y = za; }
                else     { fv.x = za; fv.y = fb; }
                ff2[(size_t)(brow + m * 16 + l4 * 4 + r) * 2048 + j] = fv;
                dsum[m][r] += sv;
            }
    }

    // ---------------- d reduction ----------------
    #pragma unroll
    for (int m = 0; m < 2; ++m)
        #pragma unroll
        for (int r = 0; r < 4; ++r) {
            float v = dsum[m][r];
            v += __shfl_xor(v, 1);
            v += __shfl_xor(v, 2);
            v += __shfl_xor(v, 4);
            v += __shfl_xor(v, 8);
            if (l15 == 0) Dred[wave * 32 + m * 16 + l4 * 4 + r] = v;
        }
    __syncthreads();
    if (tid < BM)
        d_vec[brow + tid] = Dred[tid] + Dred[32 + tid] + Dred[64 + tid] + Dred[96 + tid];
}

extern "C" void kernel_launch(void* const* d_in, const int* in_sizes, int n_in,
                              void* d_out, int out_size, void* d_ws, size_t ws_size,
                              hipStream_t stream) {
    const float* z   = (const float*)d_in[0];
    const float* sW0 = (const float*)d_in[1];
    const float* sW1 = (const float*)d_in[2];
    const float* sW2 = (const float*)d_in[3];
    const float* sb2 = (const float*)d_in[4];
    const float* tW0 = (const float*)d_in[5];
    const float* tW1 = (const float*)d_in[6];
    const float* tW2 = (const float*)d_in[7];
    const float* tb2 = (const float*)d_in[8];

    float* fout = (float*)d_out;
    float* dvec = fout + (size_t)BATCH * 4096;
    unsigned short* ws = (unsigned short*)d_ws;

    hipLaunchKernelGGL(conv_w, dim3(512), dim3(256), 0, stream,
                       sW0, sW1, sW2, tW0, tW1, tW2, ws);
    hipLaunchKernelGGL(conv_z, dim3(4096), dim3(256), 0, stream,
                       z, (char*)d_out);
    hipLaunchKernelGGL(coupling_main, dim3(BATCH / BM), dim3(256), 0, stream,
                       z, sb2, tb2, ws, fout, dvec);
}